// Round 6
// baseline (346.908 us; speedup 1.0000x reference)
//
#include <hip/hip_runtime.h>
#include <hip/hip_bf16.h>

// ---- constants for this problem ----
#define BB 4
#define TT 2048
#define C_IN 1152
#define NE 1024
#define NH 16
#define HD 64
#define MM (BB*TT)          // 8192
#define N_QKV (3*NE)        // 3072

typedef __attribute__((ext_vector_type(8))) short s16x8;
typedef __attribute__((ext_vector_type(4))) float f32x4;

static __device__ __forceinline__ unsigned short f2bf(float x) {
    unsigned int u = __float_as_uint(x);
    unsigned int r = (u + 0x7fffu + ((u >> 16) & 1u)) >> 16;
    return (unsigned short)r;
}

// async global->LDS, 16 B per lane. LDS dest = wave-uniform base + lane*16.
static __device__ __forceinline__ void async16(const void* g, void* l) {
    __builtin_amdgcn_global_load_lds((const __attribute__((address_space(1))) void*)g,
                                     (__attribute__((address_space(3))) void*)l, 16, 0, 0);
}

// ---------------- LayerNorm: x fp32 [M][C_IN] -> h bf16 [M][C_IN] ----------------
__global__ __launch_bounds__(256) void ln_kernel(const float* __restrict__ x,
                                                 const float* __restrict__ w,
                                                 const float* __restrict__ b,
                                                 unsigned short* __restrict__ h) {
    const int row = blockIdx.x;
    const float* xr = x + (size_t)row * C_IN;
    float s = 0.f, sq = 0.f;
    for (int i = threadIdx.x; i < C_IN; i += 256) {
        float v = xr[i];
        s += v; sq += v * v;
    }
    for (int off = 1; off < 64; off <<= 1) {
        s  += __shfl_xor(s, off, 64);
        sq += __shfl_xor(sq, off, 64);
    }
    __shared__ float red[2][4];
    const int wid = threadIdx.x >> 6, lane = threadIdx.x & 63;
    if (lane == 0) { red[0][wid] = s; red[1][wid] = sq; }
    __syncthreads();
    s  = red[0][0] + red[0][1] + red[0][2] + red[0][3];
    sq = red[1][0] + red[1][1] + red[1][2] + red[1][3];
    const float mu  = s * (1.f / C_IN);
    const float var = sq * (1.f / C_IN) - mu * mu;
    const float rs  = rsqrtf(var + 1e-5f);
    unsigned short* hr = h + (size_t)row * C_IN;
    for (int i = threadIdx.x; i < C_IN; i += 256) {
        float v = (xr[i] - mu) * rs * w[i] + b[i];
        hr[i] = f2bf(v);
    }
}

// ------------- transpose+cast: in fp32 [K][N] -> out bf16 [N][K] -------------
__global__ __launch_bounds__(256) void transpose_cast(const float* __restrict__ in,
                                                      unsigned short* __restrict__ out,
                                                      int K, int N) {
    __shared__ float tile[32][33];
    const int n0 = blockIdx.x * 32, k0 = blockIdx.y * 32;
    const int tx = threadIdx.x & 31, ty = threadIdx.x >> 5;   // 32 x 8
    for (int i = ty; i < 32; i += 8)
        tile[i][tx] = in[(size_t)(k0 + i) * N + n0 + tx];
    __syncthreads();
    for (int i = ty; i < 32; i += 8)
        out[(size_t)(n0 + i) * K + k0 + tx] = f2bf(tile[tx][i]);
}

#define ATT_SC 0.18033688011112042f   /* (1/8) * log2(e) */

// ------------- GEMM: A bf16 [M][K] x Bt bf16 [N][K] + bias -> epilogue -------------
// Round-0 proven 128x128 schedule (4 waves, double-buffered global_load_lds,
// one barrier per k-tile) + T1 bijective XCD swizzle.
// Round-6: FRAGMENT-MAJOR LDS. One async16 stages exactly one 16x32 MFMA
// fragment (64 lanes x 16 B; per-lane source row l16, k-chunk quad). Every
// ds_read_b128 is frag_base + lane*16 -> contiguous 1 KiB, ZERO bank conflicts
// (old row-major [row][32] layout was an 8-way conflict on every read, 7.2M/disp).
// MODE 0: QKV epilogue (q pre-scaled ATT_SC); MODE 1: LDS-routed fp32 stores.
#define EP_STRIDE 136   /* ushort; 272 B rows keep 16 B alignment for b128 */
template <int MODE>
__global__ __launch_bounds__(256) void gemm_bt(const unsigned short* __restrict__ A,
                                               const unsigned short* __restrict__ Bt,
                                               const float* __restrict__ bias,
                                               void* __restrict__ outp,
                                               unsigned short* __restrict__ kb,
                                               unsigned short* __restrict__ vt,
                                               int M, int N, int K) {
    __shared__ unsigned short smem[16384];          // 32 KB
    unsigned short* As = smem;                      // [2][8 frags][512]
    unsigned short* Bs = smem + 8192;
    const int tid = threadIdx.x;
    const int wid = tid >> 6, lane = tid & 63;
    const int wm = wid >> 1, wn = wid & 1;
    const int quad = lane >> 4, l16 = lane & 15;

    // T1: bijective XCD-chunked swizzle (nwg % 8 == 0 for both grids)
    const int gx  = gridDim.x;
    const int nwg = gx * gridDim.y;
    const int bid = blockIdx.y * gx + blockIdx.x;
    const int wg  = (bid & 7) * (nwg >> 3) + (bid >> 3);
    const int m0 = (wg / gx) * 128, n0 = (wg % gx) * 128;

    // fragment-major staging: wave wid stages frags {2wid, 2wid+1} of A and B.
    // source: row (f*16 + l16), k-chunk quad*8  (16 rows x 64 B segments)
    const unsigned short* gA = A  + (size_t)(m0 + wid * 32 + l16) * K + quad * 8;
    const unsigned short* gB = Bt + (size_t)(n0 + wid * 32 + l16) * K + quad * 8;
    const int fofs = wid * 1024;                 // 2 frags * 512 shorts

    f32x4 acc[4][4] = {};

    async16(gA,          &As[fofs]);
    async16(gA + 16 * K, &As[fofs + 512]);
    async16(gB,          &Bs[fofs]);
    async16(gB + 16 * K, &Bs[fofs + 512]);

    const int nk = K >> 5;
    for (int kt = 0; kt < nk; kt++) {
        __syncthreads();
        const int cur = kt & 1;
        if (kt + 1 < nk) {
            const int kk = (kt + 1) << 5;
            const int nxt = (cur ^ 1) * 4096;
            async16(gA + kk,          &As[nxt + fofs]);
            async16(gA + kk + 16 * K, &As[nxt + fofs + 512]);
            async16(gB + kk,          &Bs[nxt + fofs]);
            async16(gB + kk + 16 * K, &Bs[nxt + fofs + 512]);
        }
        const int cb = cur * 4096;
        s16x8 af[4], bfb[4];
        for (int mi = 0; mi < 4; mi++)
            af[mi] = *(const s16x8*)&As[cb + (wm * 4 + mi) * 512 + lane * 8];
        for (int ni = 0; ni < 4; ni++)
            bfb[ni] = *(const s16x8*)&Bs[cb + (wn * 4 + ni) * 512 + lane * 8];
        for (int mi = 0; mi < 4; mi++)
            for (int ni = 0; ni < 4; ni++)
                acc[mi][ni] = __builtin_amdgcn_mfma_f32_16x16x32_bf16(af[mi], bfb[ni], acc[mi][ni], 0, 0, 0);
    }

    // bias into registers (+ ATT_SC pre-scale for the q third)
    const int which0 = n0 >> 10;
    const float sc = (MODE == 0 && which0 == 0) ? ATT_SC : 1.0f;
    for (int ni = 0; ni < 4; ni++) {
        const float bv = bias[n0 + wn * 64 + ni * 16 + l16];
        for (int mi = 0; mi < 4; mi++)
            for (int r = 0; r < 4; r++)
                acc[mi][ni][r] = (acc[mi][ni][r] + bv) * sc;
    }

    if (MODE == 1) {
        // LDS-routed coalesced fp32 epilogue: 2 passes of 64 rows.
        float* Tf = (float*)smem;
        float* out = (float*)outp;
        for (int p = 0; p < 2; p++) {
            __syncthreads();
            if (wm == p) {
                for (int mi = 0; mi < 4; mi++)
                    for (int ni = 0; ni < 4; ni++) {
                        const int col = wn * 64 + ni * 16 + l16;
                        for (int r = 0; r < 4; r++)
                            Tf[(mi * 16 + quad * 4 + r) * 128 + col] = acc[mi][ni][r];
                    }
            }
            __syncthreads();
            const int rl = tid >> 5;          // 0..7
            const int c4 = (tid & 31) * 4;    // f32 col, 16B-aligned
            for (int rr = rl; rr < 64; rr += 8) {
                *(float4*)&out[(size_t)(m0 + p * 64 + rr) * N + n0 + c4] =
                    *(const float4*)&Tf[rr * 128 + c4];
            }
        }
        return;
    }

    // ---- MODE 0: LDS-routed coalesced epilogue ----
    const int which = n0 >> 10;                    // 0=q 1=k 2=v (uniform)
    const int bb = m0 >> 11;
    const int mloc = m0 & 2047;                    // batch-local time base
    unsigned short* T = smem;                      // [64][EP_STRIDE]

    if (which < 2) {
        // row layout [m_local 64][n_local 128]; two m-half passes
        unsigned short* qk = (which == 0) ? (unsigned short*)outp : kb;
        for (int pass = 0; pass < 2; pass++) {
            __syncthreads();
            if (wm == pass) {
                for (int mi = 0; mi < 4; mi++)
                    for (int ni = 0; ni < 4; ni++) {
                        const int nl = wn * 64 + ni * 16 + l16;
                        for (int r = 0; r < 4; r++)
                            T[(mi * 16 + quad * 4 + r) * EP_STRIDE + nl] = f2bf(acc[mi][ni][r]);
                    }
            }
            __syncthreads();
            const int ml = tid >> 2, c = tid & 3;
            const int t  = mloc + pass * 64 + ml;
            const int nl0 = c * 32;
            const int hh = ((n0 & 1023) >> 6) + (nl0 >> 6);
            const int d0 = nl0 & 63;
            unsigned short* dst = qk + ((size_t)(bb * 16 + hh) * TT + t) * HD + d0;
            const unsigned short* src = &T[ml * EP_STRIDE + nl0];
            for (int u = 0; u < 4; u++)
                *(s16x8*)(dst + u * 8) = *(const s16x8*)(src + u * 8);
        }
    } else {
        // transposed layout [n_local 64][m_local 128]; two n-half passes
        for (int pass = 0; pass < 2; pass++) {
            __syncthreads();
            if (wn == pass) {
                for (int mi = 0; mi < 4; mi++)
                    for (int ni = 0; ni < 4; ni++) {
                        const int nlh = ni * 16 + l16;
                        const int mlb = wm * 64 + mi * 16 + quad * 4;
                        for (int r = 0; r < 4; r += 2) {
                            const unsigned int pk = (unsigned int)f2bf(acc[mi][ni][r]) |
                                                    ((unsigned int)f2bf(acc[mi][ni][r + 1]) << 16);
                            *(unsigned int*)&T[nlh * EP_STRIDE + mlb + r] = pk;
                        }
                    }
            }
            __syncthreads();
            const int nlh = tid >> 2, c = tid & 3;
            const int hh = (n0 - 2048 + pass * 64) >> 6;
            unsigned short* dst = vt + ((size_t)(bb * 16 + hh) * HD + nlh) * TT + mloc + c * 32;
            const unsigned short* src = &T[nlh * EP_STRIDE + c * 32];
            for (int u = 0; u < 4; u++)
                *(s16x8*)(dst + u * 8) = *(const s16x8*)(src + u * 8);
        }
    }
}

// ------------- flash attention: S^T trick + ones-MFMA row sums -------------
// Round-0 proven schedule (2-buffer __syncthreads staging, per-mf fence+PV)
// + diag-hoisted causal mask (round 5)
// + round-6 FRAGMENT-MAJOR K/V LDS: one async16 = one 16x32 fragment; reads are
//   frag_base + lane*16, zero bank conflicts (replaces the XOR-chunk layout whose
//   reads were 8-way-conflicted, 3.24M/dispatch).
#define PST 72                         /* shorts; 144 B rows, 16B-aligned */

__global__ __launch_bounds__(256) void attn_kernel(const unsigned short* __restrict__ qb,
                                                   const unsigned short* __restrict__ kb,
                                                   const unsigned short* __restrict__ vt,
                                                   unsigned short* __restrict__ yb) {
    __shared__ unsigned short Ks[2][8 * 512];        // 8 frags per 64x64 tile
    __shared__ unsigned short Vs[2][8 * 512];
    __shared__ unsigned short Ps[4][2 * 16 * PST];   // per-wave, per-mf [16 q][PST]
    const int tid = threadIdx.x, wid = tid >> 6, lane = tid & 63;
    const int quad = lane >> 4, l16 = lane & 15;
    const int bh = blockIdx.x & 63;
    const int qblk = 15 - (blockIdx.x >> 6);         // longest-first (LPT packing)

    const unsigned short* qh = qb + (size_t)bh * TT * HD;
    const unsigned short* kh = kb + (size_t)bh * TT * HD;
    const unsigned short* vh = vt + (size_t)bh * HD * TT;
    unsigned short* ps = Ps[wid];

    const int q0w = qblk * 128 + wid * 32;           // this wave's 32 q-rows
    s16x8 aq[2][2];
    #pragma unroll
    for (int mf = 0; mf < 2; mf++) {
        aq[mf][0] = *(const s16x8*)&qh[(size_t)(q0w + mf * 16 + l16) * HD + quad * 8];
        aq[mf][1] = *(const s16x8*)&qh[(size_t)(q0w + mf * 16 + l16) * HD + 32 + quad * 8];
    }
    // ones B-frag (bf16 1.0 = 0x3F80)
    s16x8 onesf;
    #pragma unroll
    for (int i = 0; i < 8; i++) onesf[i] = (short)0x3F80;

    f32x4 yacc[2][4] = {};
    f32x4 lacc[2] = {};                              // row-sum accumulators
    const int ntiles = 2 * qblk + 2;                 // always even

    // fragment-major staging: wave wid stages K-frags (nj=wid, h=0/1) and
    // V-frags (ni=wid, h=0/1). Per-lane source = row (wid*16+l16), chunk quad.
    const unsigned short* kp0 = kh + (size_t)(wid * 16 + l16) * HD + quad * 8;
    const unsigned short* vp0 = vh + (size_t)(wid * 16 + l16) * TT + quad * 8;
    const int ldsF = wid * 1024;                     // frags 2wid, 2wid+1

    // prologue: stage tile 0 into buffer 0; bump to tile 1
    async16(kp0,      &Ks[0][ldsF]);  async16(kp0 + 32, &Ks[0][ldsF + 512]);
    async16(vp0,      &Vs[0][ldsF]);  async16(vp0 + 32, &Vs[0][ldsF + 512]);
    kp0 += 64 * HD; vp0 += 64;

#define ATT_STEP(CUR, TT_)                                                              \
    {                                                                                   \
        __syncthreads();                                                                \
        if ((TT_) + 1 < ntiles) {                                                       \
            async16(kp0,      &Ks[(CUR) ^ 1][ldsF]);                                    \
            async16(kp0 + 32, &Ks[(CUR) ^ 1][ldsF + 512]);                              \
            async16(vp0,      &Vs[(CUR) ^ 1][ldsF]);                                    \
            async16(vp0 + 32, &Vs[(CUR) ^ 1][ldsF + 512]);                              \
            kp0 += 64 * HD; vp0 += 64;                                                  \
        }                                                                               \
        const int tk0 = (TT_) * 64;                                                     \
        if (tk0 <= q0w + 31) {                                                          \
            const unsigned short* Kc = Ks[CUR];                                         \
            const unsigned short* Vc = Vs[CUR];                                         \
            s16x8 kf[4][2], vf[4][2];                                                   \
            _Pragma("unroll")                                                           \
            for (int nj = 0; nj < 4; nj++) {                                            \
                kf[nj][0] = *(const s16x8*)&Kc[(nj * 2 + 0) * 512 + lane * 8];          \
                kf[nj][1] = *(const s16x8*)&Kc[(nj * 2 + 1) * 512 + lane * 8];          \
            }                                                                           \
            _Pragma("unroll")                                                           \
            for (int ni = 0; ni < 4; ni++) {                                            \
                vf[ni][0] = *(const s16x8*)&Vc[(ni * 2 + 0) * 512 + lane * 8];          \
                vf[ni][1] = *(const s16x8*)&Vc[(ni * 2 + 1) * 512 + lane * 8];          \
            }                                                                           \
            _Pragma("unroll")                                                           \
            for (int mf = 0; mf < 2; mf++) {                                            \
                const int f0 = q0w + mf * 16;                                           \
                if (tk0 > f0 + 15) continue;                                            \
                unsigned short* pm = ps + mf * (16 * PST);                              \
                const int qg = f0 + l16;                                                \
                f32x4 st[4];                                                            \
                _Pragma("unroll")                                                       \
                for (int nj = 0; nj < 4; nj++) {                                        \
                    f32x4 z = {};                                                       \
                    z = __builtin_amdgcn_mfma_f32_16x16x32_bf16(kf[nj][0], aq[mf][0], z, 0, 0, 0); \
                    z = __builtin_amdgcn_mfma_f32_16x16x32_bf16(kf[nj][1], aq[mf][1], z, 0, 0, 0); \
                    st[nj] = z;                                                         \
                }                                                                       \
                const bool diag = (tk0 + 64 > f0);                                      \
                float pv[4][4];                                                         \
                _Pragma("unroll")                                                       \
                for (int nj = 0; nj < 4; nj++)                                          \
                    _Pragma("unroll")                                                   \
                    for (int r = 0; r < 4; r++)                                         \
                        pv[nj][r] = exp2f(st[nj][r]);                                   \
                if (diag) {                                                             \
                    _Pragma("unroll")                                                   \
                    for (int nj = 0; nj < 4; nj++) {                                    \
                        const int keyb = tk0 + nj * 16 + quad * 4;                      \
                        _Pragma("unroll")                                               \
                        for (int r = 0; r < 4; r++)                                     \
                            if (keyb + r > qg) pv[nj][r] = 0.f;                         \
                    }                                                                   \
                }                                                                       \
                _Pragma("unroll")                                                       \
                for (int nj = 0; nj < 4; nj++) {                                        \
                    const unsigned int pk0 = __builtin_amdgcn_perm(                     \
                        __float_as_uint(pv[nj][1]), __float_as_uint(pv[nj][0]), 0x07060302u); \
                    const unsigned int pk1 = __builtin_amdgcn_perm(                     \
                        __float_as_uint(pv[nj][3]), __float_as_uint(pv[nj][2]), 0x07060302u); \
                    *(uint2*)&pm[l16 * PST + nj * 16 + quad * 4] = make_uint2(pk0, pk1);\
                }                                                                       \
                __asm volatile("s_waitcnt lgkmcnt(0)" ::: "memory");                    \
                const s16x8 ap0 = *(const s16x8*)&pm[l16 * PST + quad * 8];             \
                const s16x8 ap1 = *(const s16x8*)&pm[l16 * PST + 32 + quad * 8];        \
                lacc[mf] = __builtin_amdgcn_mfma_f32_16x16x32_bf16(ap0, onesf, lacc[mf], 0, 0, 0); \
                lacc[mf] = __builtin_amdgcn_mfma_f32_16x16x32_bf16(ap1, onesf, lacc[mf], 0, 0, 0); \
                _Pragma("unroll")                                                       \
                for (int ni = 0; ni < 4; ni++) {                                        \
                    yacc[mf][ni] = __builtin_amdgcn_mfma_f32_16x16x32_bf16(ap0, vf[ni][0], yacc[mf][ni], 0, 0, 0); \
                    yacc[mf][ni] = __builtin_amdgcn_mfma_f32_16x16x32_bf16(ap1, vf[ni][1], yacc[mf][ni], 0, 0, 0); \
                }                                                                       \
            }                                                                           \
        }                                                                               \
    }

    for (int t = 0; t < ntiles; t += 2) {
        ATT_STEP(0, t);
        ATT_STEP(1, t + 1);
    }
#undef ATT_STEP

    // epilogue: lacc[mf][r] is the denominator for q = f0 + quad*4 + r — the exact
    // same (quad,r) indexing as yacc. No cross-lane reduction needed.
    const int bbi = bh >> 4, hh = bh & 15;
    #pragma unroll
    for (int mf = 0; mf < 2; mf++) {
        float linv[4];
        #pragma unroll
        for (int r = 0; r < 4; r++)
            linv[r] = 1.0f / lacc[mf][r];
        #pragma unroll
        for (int ni = 0; ni < 4; ni++)
            #pragma unroll
            for (int r = 0; r < 4; r++) {
                const int trow = q0w + mf * 16 + quad * 4 + r;
                yb[((size_t)bbi * TT + trow) * NE + hh * HD + ni * 16 + l16] =
                    f2bf(yacc[mf][ni][r] * linv[r]);
            }
    }
}

extern "C" void kernel_launch(void* const* d_in, const int* in_sizes, int n_in,
                              void* d_out, int out_size, void* d_ws, size_t ws_size,
                              hipStream_t stream) {
    const float* x      = (const float*)d_in[0];
    const float* ln_w   = (const float*)d_in[1];
    const float* ln_b   = (const float*)d_in[2];
    const float* W_attn = (const float*)d_in[3];
    const float* b_attn = (const float*)d_in[4];
    const float* W_proj = (const float*)d_in[5];
    const float* b_proj = (const float*)d_in[6];
    float* out = (float*)d_out;

    char* ws = (char*)d_ws;
    unsigned short* h    = (unsigned short*)ws;  ws += (size_t)MM * C_IN * 2;
    unsigned short* Wat  = (unsigned short*)ws;  ws += (size_t)N_QKV * C_IN * 2;
    unsigned short* Wpt  = (unsigned short*)ws;  ws += (size_t)NE * NE * 2;
    unsigned short* qbuf = (unsigned short*)ws;  ws += (size_t)MM * NE * 2;
    unsigned short* kbuf = (unsigned short*)ws;  ws += (size_t)MM * NE * 2;
    unsigned short* vtbf = (unsigned short*)ws;  ws += (size_t)MM * NE * 2;
    unsigned short* ybuf = (unsigned short*)ws;  ws += (size_t)MM * NE * 2;

    ln_kernel<<<MM, 256, 0, stream>>>(x, ln_w, ln_b, h);
    transpose_cast<<<dim3(N_QKV / 32, C_IN / 32), 256, 0, stream>>>(W_attn, Wat, C_IN, N_QKV);
    transpose_cast<<<dim3(NE / 32, NE / 32), 256, 0, stream>>>(W_proj, Wpt, NE, NE);
    gemm_bt<0><<<dim3(N_QKV / 128, MM / 128), 256, 0, stream>>>(h, Wat, b_attn, qbuf, kbuf, vtbf,
                                                                MM, N_QKV, C_IN);
    attn_kernel<<<64 * 16, 256, 0, stream>>>(qbuf, kbuf, vtbf, ybuf);
    gemm_bt<1><<<dim3(NE / 128, MM / 128), 256, 0, stream>>>(ybuf, Wpt, b_proj, out, nullptr, nullptr,
                                                             MM, NE, NE);
}

// Round 8
// 299.309 us; speedup vs baseline: 1.1590x; 1.1590x over previous
//
#include <hip/hip_runtime.h>
#include <hip/hip_bf16.h>

// ---- constants for this problem ----
#define BB 4
#define TT 2048
#define C_IN 1152
#define NE 1024
#define NH 16
#define HD 64
#define MM (BB*TT)          // 8192
#define N_QKV (3*NE)        // 3072

typedef __attribute__((ext_vector_type(8))) short s16x8;
typedef __attribute__((ext_vector_type(4))) float f32x4;

static __device__ __forceinline__ unsigned short f2bf(float x) {
    unsigned int u = __float_as_uint(x);
    unsigned int r = (u + 0x7fffu + ((u >> 16) & 1u)) >> 16;
    return (unsigned short)r;
}

// async global->LDS, 16 B per lane. LDS dest = wave-uniform base + lane*16.
static __device__ __forceinline__ void async16(const void* g, void* l) {
    __builtin_amdgcn_global_load_lds((const __attribute__((address_space(1))) void*)g,
                                     (__attribute__((address_space(3))) void*)l, 16, 0, 0);
}

// ---------------- LayerNorm: x fp32 [M][C_IN] -> h bf16 [M][C_IN] ----------------
__global__ __launch_bounds__(256) void ln_kernel(const float* __restrict__ x,
                                                 const float* __restrict__ w,
                                                 const float* __restrict__ b,
                                                 unsigned short* __restrict__ h) {
    const int row = blockIdx.x;
    const float* xr = x + (size_t)row * C_IN;
    float s = 0.f, sq = 0.f;
    for (int i = threadIdx.x; i < C_IN; i += 256) {
        float v = xr[i];
        s += v; sq += v * v;
    }
    for (int off = 1; off < 64; off <<= 1) {
        s  += __shfl_xor(s, off, 64);
        sq += __shfl_xor(sq, off, 64);
    }
    __shared__ float red[2][4];
    const int wid = threadIdx.x >> 6, lane = threadIdx.x & 63;
    if (lane == 0) { red[0][wid] = s; red[1][wid] = sq; }
    __syncthreads();
    s  = red[0][0] + red[0][1] + red[0][2] + red[0][3];
    sq = red[1][0] + red[1][1] + red[1][2] + red[1][3];
    const float mu  = s * (1.f / C_IN);
    const float var = sq * (1.f / C_IN) - mu * mu;
    const float rs  = rsqrtf(var + 1e-5f);
    unsigned short* hr = h + (size_t)row * C_IN;
    for (int i = threadIdx.x; i < C_IN; i += 256) {
        float v = (xr[i] - mu) * rs * w[i] + b[i];
        hr[i] = f2bf(v);
    }
}

// ------------- transpose+cast: in fp32 [K][N] -> out bf16 [N][K] -------------
__global__ __launch_bounds__(256) void transpose_cast(const float* __restrict__ in,
                                                      unsigned short* __restrict__ out,
                                                      int K, int N) {
    __shared__ float tile[32][33];
    const int n0 = blockIdx.x * 32, k0 = blockIdx.y * 32;
    const int tx = threadIdx.x & 31, ty = threadIdx.x >> 5;   // 32 x 8
    for (int i = ty; i < 32; i += 8)
        tile[i][tx] = in[(size_t)(k0 + i) * N + n0 + tx];
    __syncthreads();
    for (int i = ty; i < 32; i += 8)
        out[(size_t)(n0 + i) * K + k0 + tx] = f2bf(tile[tx][i]);
}

#define ATT_SC 0.18033688011112042f   /* (1/8) * log2(e) */

// ------------- GEMM: A bf16 [M][K] x Bt bf16 [N][K] + bias -> epilogue -------------
// Round-7/8: BK=64, XOR-swizzled 128-B LDS rows (the m214/G4 pattern, proven in
// this problem's attn K-path):
//  - stage: one async16 = 8 rows x 128 B contiguous LDS; source lanes 8-per-row
//    (contiguous 128-B window, coalescing-safe), chunk ^= (row&7) within the row.
//    LDS[row][sc] = global[row][sc ^ (row&7)].
//  - read: fragment chunk q of row r at LDS[r][q ^ (r&7)]; each consecutive
//    8-lane group covers all 8 granule positions mod the 128-B bank period ->
//    conflict-free. Kills round-5's 8-way conflicts (7.2M/disp) without
//    round-6's scattered-fetch penalty (96 MB FETCH).
//  - barriers halve (BK 32 -> 64). Same proven double-buffer __syncthreads loop.
// MODE 0: QKV epilogue (q pre-scaled ATT_SC); MODE 1: LDS-routed fp32 stores.
#define EP_STRIDE 136   /* ushort; 272 B rows keep 16 B alignment for b128 */
template <int MODE>
__global__ __launch_bounds__(256) void gemm_bt(const unsigned short* __restrict__ A,
                                               const unsigned short* __restrict__ Bt,
                                               const float* __restrict__ bias,
                                               void* __restrict__ outp,
                                               unsigned short* __restrict__ kb,
                                               unsigned short* __restrict__ vt,
                                               int M, int N, int K) {
    __shared__ unsigned short smem[32768];   // 64 KB: [2 buf][ A 8192 | B 8192 ]
    const int tid = threadIdx.x;
    const int wid = tid >> 6, lane = tid & 63;
    const int wm = wid >> 1, wn = wid & 1;
    const int quad = lane >> 4, l16 = lane & 15;

    // T1: bijective XCD-chunked swizzle (nwg % 8 == 0 for both grids)
    const int gx  = gridDim.x;
    const int nwg = gx * gridDim.y;
    const int bid = blockIdx.y * gx + blockIdx.x;
    const int wg  = (bid & 7) * (nwg >> 3) + (bid >> 3);
    const int m0 = (wg / gx) * 128, n0 = (wg % gx) * 128;

    // staging: wave wid covers rows wid*32 + j*8 + rl (j=0..3); 8 lanes per row,
    // chunk sc XOR'd by row&7 (within the row's 128-B window -> coalesced).
    const int rl = lane >> 3;                     // 0..7
    const int sc = (lane & 7) ^ rl;               // stored chunk index
    const unsigned short* gA = A  + (size_t)(m0 + wid * 32 + rl) * K + sc * 8;
    const unsigned short* gB = Bt + (size_t)(n0 + wid * 32 + rl) * K + sc * 8;

    f32x4 acc[4][4] = {};
    const int nk = K >> 6;

    // per-thread read chunk indices (inverse XOR): row&7 == l16&7 for all frags
    const int sc0 = (quad ^ (l16 & 7)) * 8;
    const int sc1 = ((4 + quad) ^ (l16 & 7)) * 8;

#define STAGE(KT, BUF)                                                          \
    {                                                                           \
        const unsigned short* a_ = gA + (KT) * 64;                              \
        const unsigned short* b_ = gB + (KT) * 64;                              \
        unsigned short* sa_ = &smem[(BUF) * 16384 + wid * 2048];                \
        unsigned short* sb_ = &smem[(BUF) * 16384 + 8192 + wid * 2048];         \
        _Pragma("unroll")                                                       \
        for (int j = 0; j < 4; j++) {                                           \
            async16(a_ + (size_t)(j * 8) * K, sa_ + j * 512);                   \
            async16(b_ + (size_t)(j * 8) * K, sb_ + j * 512);                   \
        }                                                                       \
    }

    STAGE(0, 0);

    for (int kt = 0; kt < nk; kt++) {
        __syncthreads();
        const int cur = kt & 1;
        if (kt + 1 < nk) STAGE(kt + 1, cur ^ 1);

        const unsigned short* As_ = &smem[cur * 16384];
        const unsigned short* Bs_ = &smem[cur * 16384 + 8192];
        #pragma unroll
        for (int h = 0; h < 2; h++) {
            const int sch = h ? sc1 : sc0;
            s16x8 af[4], bfb[4];
            #pragma unroll
            for (int mi = 0; mi < 4; mi++)
                af[mi] = *(const s16x8*)&As_[(wm * 64 + mi * 16 + l16) * 64 + sch];
            #pragma unroll
            for (int ni = 0; ni < 4; ni++)
                bfb[ni] = *(const s16x8*)&Bs_[(wn * 64 + ni * 16 + l16) * 64 + sch];
            #pragma unroll
            for (int mi = 0; mi < 4; mi++)
                #pragma unroll
                for (int ni = 0; ni < 4; ni++)
                    acc[mi][ni] = __builtin_amdgcn_mfma_f32_16x16x32_bf16(af[mi], bfb[ni], acc[mi][ni], 0, 0, 0);
        }
    }
#undef STAGE

    // bias into registers (+ ATT_SC pre-scale for the q third)
    const int which0 = n0 >> 10;
    const float sc_ = (MODE == 0 && which0 == 0) ? ATT_SC : 1.0f;
    for (int ni = 0; ni < 4; ni++) {
        const float bv = bias[n0 + wn * 64 + ni * 16 + l16];
        for (int mi = 0; mi < 4; mi++)
            for (int r = 0; r < 4; r++)
                acc[mi][ni][r] = (acc[mi][ni][r] + bv) * sc_;
    }

    if (MODE == 1) {
        // LDS-routed coalesced fp32 epilogue: 2 passes of 64 rows.
        float* Tf = (float*)smem;
        float* out = (float*)outp;
        for (int p = 0; p < 2; p++) {
            __syncthreads();
            if (wm == p) {
                for (int mi = 0; mi < 4; mi++)
                    for (int ni = 0; ni < 4; ni++) {
                        const int col = wn * 64 + ni * 16 + l16;
                        for (int r = 0; r < 4; r++)
                            Tf[(mi * 16 + quad * 4 + r) * 128 + col] = acc[mi][ni][r];
                    }
            }
            __syncthreads();
            const int rlo = tid >> 5;         // 0..7
            const int c4 = (tid & 31) * 4;    // f32 col, 16B-aligned
            for (int rr = rlo; rr < 64; rr += 8) {
                *(float4*)&out[(size_t)(m0 + p * 64 + rr) * N + n0 + c4] =
                    *(const float4*)&Tf[rr * 128 + c4];
            }
        }
        return;
    }

    // ---- MODE 0: LDS-routed coalesced epilogue ----
    const int which = n0 >> 10;                    // 0=q 1=k 2=v (uniform)
    const int bb = m0 >> 11;
    const int mloc = m0 & 2047;                    // batch-local time base
    unsigned short* T = smem;                      // [64][EP_STRIDE]

    if (which < 2) {
        // row layout [m_local 64][n_local 128]; two m-half passes
        unsigned short* qk = (which == 0) ? (unsigned short*)outp : kb;
        for (int pass = 0; pass < 2; pass++) {
            __syncthreads();
            if (wm == pass) {
                for (int mi = 0; mi < 4; mi++)
                    for (int ni = 0; ni < 4; ni++) {
                        const int nl = wn * 64 + ni * 16 + l16;
                        for (int r = 0; r < 4; r++)
                            T[(mi * 16 + quad * 4 + r) * EP_STRIDE + nl] = f2bf(acc[mi][ni][r]);
                    }
            }
            __syncthreads();
            const int ml = tid >> 2, c = tid & 3;
            const int t  = mloc + pass * 64 + ml;
            const int nl0 = c * 32;
            const int hh = ((n0 & 1023) >> 6) + (nl0 >> 6);
            const int d0 = nl0 & 63;
            unsigned short* dst = qk + ((size_t)(bb * 16 + hh) * TT + t) * HD + d0;
            const unsigned short* src = &T[ml * EP_STRIDE + nl0];
            for (int u = 0; u < 4; u++)
                *(s16x8*)(dst + u * 8) = *(const s16x8*)(src + u * 8);
        }
    } else {
        // transposed layout [n_local 64][m_local 128]; two n-half passes
        for (int pass = 0; pass < 2; pass++) {
            __syncthreads();
            if (wn == pass) {
                for (int mi = 0; mi < 4; mi++)
                    for (int ni = 0; ni < 4; ni++) {
                        const int nlh = ni * 16 + l16;
                        const int mlb = wm * 64 + mi * 16 + quad * 4;
                        for (int r = 0; r < 4; r += 2) {
                            const unsigned int pk = (unsigned int)f2bf(acc[mi][ni][r]) |
                                                    ((unsigned int)f2bf(acc[mi][ni][r + 1]) << 16);
                            *(unsigned int*)&T[nlh * EP_STRIDE + mlb + r] = pk;
                        }
                    }
            }
            __syncthreads();
            const int nlh = tid >> 2, c = tid & 3;
            const int hh = (n0 - 2048 + pass * 64) >> 6;
            unsigned short* dst = vt + ((size_t)(bb * 16 + hh) * HD + nlh) * TT + mloc + c * 32;
            const unsigned short* src = &T[nlh * EP_STRIDE + c * 32];
            for (int u = 0; u < 4; u++)
                *(s16x8*)(dst + u * 8) = *(const s16x8*)(src + u * 8);
        }
    }
}

// ------------- flash attention: S^T trick + ones-MFMA row sums -------------
// Round-5 proven version: round-0 schedule (2-buffer __syncthreads staging,
// XOR-swizzled K/V, per-mf fence+PV) + diag-hoisted causal mask.
#define PST 72                         /* shorts; 144 B rows, 16B-aligned */

__global__ __launch_bounds__(256) void attn_kernel(const unsigned short* __restrict__ qb,
                                                   const unsigned short* __restrict__ kb,
                                                   const unsigned short* __restrict__ vt,
                                                   unsigned short* __restrict__ yb) {
    __shared__ unsigned short Ks[2][64 * 64];
    __shared__ unsigned short Vs[2][64 * 64];
    __shared__ unsigned short Ps[4][2 * 16 * PST];   // per-wave, per-mf [16 q][PST]
    const int tid = threadIdx.x, wid = tid >> 6, lane = tid & 63;
    const int quad = lane >> 4, l16 = lane & 15;
    const int bh = blockIdx.x & 63;
    const int qblk = 15 - (blockIdx.x >> 6);         // longest-first (LPT packing)

    const unsigned short* qh = qb + (size_t)bh * TT * HD;
    const unsigned short* kh = kb + (size_t)bh * TT * HD;
    const unsigned short* vh = vt + (size_t)bh * HD * TT;
    unsigned short* ps = Ps[wid];

    const int q0w = qblk * 128 + wid * 32;           // this wave's 32 q-rows
    s16x8 aq[2][2];
    #pragma unroll
    for (int mf = 0; mf < 2; mf++) {
        aq[mf][0] = *(const s16x8*)&qh[(size_t)(q0w + mf * 16 + l16) * HD + quad * 8];
        aq[mf][1] = *(const s16x8*)&qh[(size_t)(q0w + mf * 16 + l16) * HD + 32 + quad * 8];
    }
    // ones B-frag (bf16 1.0 = 0x3F80)
    s16x8 onesf;
    #pragma unroll
    for (int i = 0; i < 8; i++) onesf[i] = (short)0x3F80;

    f32x4 yacc[2][4] = {};
    f32x4 lacc[2] = {};                              // row-sum accumulators
    const int ntiles = 2 * qblk + 2;                 // always even

    // staging: row r = wid*16 + {0,8} + rl, chunk cc XOR-swizzled; pointers bumped
    const int rl = lane >> 3;
    const int cc = (lane & 7) ^ (rl & 7);
    const unsigned short* kp0 = kh + (size_t)(wid * 16 + rl) * HD + cc * 8;
    const unsigned short* kp1 = kh + (size_t)(wid * 16 + 8 + rl) * HD + cc * 8;
    const unsigned short* vp0 = vh + (size_t)(wid * 16 + rl) * TT + cc * 8;
    const unsigned short* vp1 = vh + (size_t)(wid * 16 + 8 + rl) * TT + cc * 8;
    const int ldsK0 = wid * 16 * 64, ldsK1 = (wid * 16 + 8) * 64;

    // prologue: stage tile 0 into buffer 0; bump to tile 1
    async16(kp0, &Ks[0][ldsK0]);  async16(kp1, &Ks[0][ldsK1]);
    async16(vp0, &Vs[0][ldsK0]);  async16(vp1, &Vs[0][ldsK1]);
    kp0 += 64 * HD; kp1 += 64 * HD; vp0 += 64; vp1 += 64;

    const int p0s = quad ^ (l16 & 7);
    const int p1s = (4 + quad) ^ (l16 & 7);

#define ATT_STEP(CUR, TT_)                                                              \
    {                                                                                   \
        __syncthreads();                                                                \
        if ((TT_) + 1 < ntiles) {                                                       \
            async16(kp0, &Ks[(CUR) ^ 1][ldsK0]);  async16(kp1, &Ks[(CUR) ^ 1][ldsK1]);  \
            async16(vp0, &Vs[(CUR) ^ 1][ldsK0]);  async16(vp1, &Vs[(CUR) ^ 1][ldsK1]);  \
            kp0 += 64 * HD; kp1 += 64 * HD; vp0 += 64; vp1 += 64;                       \
        }                                                                               \
        const int tk0 = (TT_) * 64;                                                     \
        if (tk0 <= q0w + 31) {                                                          \
            const unsigned short* Kc = Ks[CUR];                                         \
            const unsigned short* Vc = Vs[CUR];                                         \
            s16x8 kf[4][2], vf[4][2];                                                   \
            _Pragma("unroll")                                                           \
            for (int nj = 0; nj < 4; nj++) {                                            \
                kf[nj][0] = *(const s16x8*)&Kc[(nj * 16 + l16) * 64 + p0s * 8];         \
                kf[nj][1] = *(const s16x8*)&Kc[(nj * 16 + l16) * 64 + p1s * 8];         \
            }                                                                           \
            _Pragma("unroll")                                                           \
            for (int ni = 0; ni < 4; ni++) {                                            \
                vf[ni][0] = *(const s16x8*)&Vc[(ni * 16 + l16) * 64 + p0s * 8];         \
                vf[ni][1] = *(const s16x8*)&Vc[(ni * 16 + l16) * 64 + p1s * 8];         \
            }                                                                           \
            _Pragma("unroll")                                                           \
            for (int mf = 0; mf < 2; mf++) {                                            \
                const int f0 = q0w + mf * 16;                                           \
                if (tk0 > f0 + 15) continue;                                            \
                unsigned short* pm = ps + mf * (16 * PST);                              \
                const int qg = f0 + l16;                                                \
                f32x4 st[4];                                                            \
                _Pragma("unroll")                                                       \
                for (int nj = 0; nj < 4; nj++) {                                        \
                    f32x4 z = {};                                                       \
                    z = __builtin_amdgcn_mfma_f32_16x16x32_bf16(kf[nj][0], aq[mf][0], z, 0, 0, 0); \
                    z = __builtin_amdgcn_mfma_f32_16x16x32_bf16(kf[nj][1], aq[mf][1], z, 0, 0, 0); \
                    st[nj] = z;                                                         \
                }                                                                       \
                const bool diag = (tk0 + 64 > f0);                                      \
                float pv[4][4];                                                         \
                _Pragma("unroll")                                                       \
                for (int nj = 0; nj < 4; nj++)                                          \
                    _Pragma("unroll")                                                   \
                    for (int r = 0; r < 4; r++)                                         \
                        pv[nj][r] = exp2f(st[nj][r]);                                   \
                if (diag) {                                                             \
                    _Pragma("unroll")                                                   \
                    for (int nj = 0; nj < 4; nj++) {                                    \
                        const int keyb = tk0 + nj * 16 + quad * 4;                      \
                        _Pragma("unroll")                                               \
                        for (int r = 0; r < 4; r++)                                     \
                            if (keyb + r > qg) pv[nj][r] = 0.f;                         \
                    }                                                                   \
                }                                                                       \
                _Pragma("unroll")                                                       \
                for (int nj = 0; nj < 4; nj++) {                                        \
                    const unsigned int pk0 = __builtin_amdgcn_perm(                     \
                        __float_as_uint(pv[nj][1]), __float_as_uint(pv[nj][0]), 0x07060302u); \
                    const unsigned int pk1 = __builtin_amdgcn_perm(                     \
                        __float_as_uint(pv[nj][3]), __float_as_uint(pv[nj][2]), 0x07060302u); \
                    *(uint2*)&pm[l16 * PST + nj * 16 + quad * 4] = make_uint2(pk0, pk1);\
                }                                                                       \
                __asm volatile("s_waitcnt lgkmcnt(0)" ::: "memory");                    \
                const s16x8 ap0 = *(const s16x8*)&pm[l16 * PST + quad * 8];             \
                const s16x8 ap1 = *(const s16x8*)&pm[l16 * PST + 32 + quad * 8];        \
                lacc[mf] = __builtin_amdgcn_mfma_f32_16x16x32_bf16(ap0, onesf, lacc[mf], 0, 0, 0); \
                lacc[mf] = __builtin_amdgcn_mfma_f32_16x16x32_bf16(ap1, onesf, lacc[mf], 0, 0, 0); \
                _Pragma("unroll")                                                       \
                for (int ni = 0; ni < 4; ni++) {                                        \
                    yacc[mf][ni] = __builtin_amdgcn_mfma_f32_16x16x32_bf16(ap0, vf[ni][0], yacc[mf][ni], 0, 0, 0); \
                    yacc[mf][ni] = __builtin_amdgcn_mfma_f32_16x16x32_bf16(ap1, vf[ni][1], yacc[mf][ni], 0, 0, 0); \
                }                                                                       \
            }                                                                           \
        }                                                                               \
    }

    for (int t = 0; t < ntiles; t += 2) {
        ATT_STEP(0, t);
        ATT_STEP(1, t + 1);
    }
#undef ATT_STEP

    // epilogue: lacc[mf][r] is the denominator for q = f0 + quad*4 + r — the exact
    // same (quad,r) indexing as yacc. No cross-lane reduction needed.
    const int bbi = bh >> 4, hh = bh & 15;
    #pragma unroll
    for (int mf = 0; mf < 2; mf++) {
        float linv[4];
        #pragma unroll
        for (int r = 0; r < 4; r++)
            linv[r] = 1.0f / lacc[mf][r];
        #pragma unroll
        for (int ni = 0; ni < 4; ni++)
            #pragma unroll
            for (int r = 0; r < 4; r++) {
                const int trow = q0w + mf * 16 + quad * 4 + r;
                yb[((size_t)bbi * TT + trow) * NE + hh * HD + ni * 16 + l16] =
                    f2bf(yacc[mf][ni][r] * linv[r]);
            }
    }
}

extern "C" void kernel_launch(void* const* d_in, const int* in_sizes, int n_in,
                              void* d_out, int out_size, void* d_ws, size_t ws_size,
                              hipStream_t stream) {
    const float* x      = (const float*)d_in[0];
    const float* ln_w   = (const float*)d_in[1];
    const float* ln_b   = (const float*)d_in[2];
    const float* W_attn = (const float*)d_in[3];
    const float* b_attn = (const float*)d_in[4];
    const float* W_proj = (const float*)d_in[5];
    const float* b_proj = (const float*)d_in[6];
    float* out = (float*)d_out;

    char* ws = (char*)d_ws;
    unsigned short* h    = (unsigned short*)ws;  ws += (size_t)MM * C_IN * 2;
    unsigned short* Wat  = (unsigned short*)ws;  ws += (size_t)N_QKV * C_IN * 2;
    unsigned short* Wpt  = (unsigned short*)ws;  ws += (size_t)NE * NE * 2;
    unsigned short* qbuf = (unsigned short*)ws;  ws += (size_t)MM * NE * 2;
    unsigned short* kbuf = (unsigned short*)ws;  ws += (size_t)MM * NE * 2;
    unsigned short* vtbf = (unsigned short*)ws;  ws += (size_t)MM * NE * 2;
    unsigned short* ybuf = (unsigned short*)ws;  ws += (size_t)MM * NE * 2;

    ln_kernel<<<MM, 256, 0, stream>>>(x, ln_w, ln_b, h);
    transpose_cast<<<dim3(N_QKV / 32, C_IN / 32), 256, 0, stream>>>(W_attn, Wat, C_IN, N_QKV);
    transpose_cast<<<dim3(NE / 32, NE / 32), 256, 0, stream>>>(W_proj, Wpt, NE, NE);
    gemm_bt<0><<<dim3(N_QKV / 128, MM / 128), 256, 0, stream>>>(h, Wat, b_attn, qbuf, kbuf, vtbf,
                                                                MM, N_QKV, C_IN);
    attn_kernel<<<64 * 16, 256, 0, stream>>>(qbuf, kbuf, vtbf, ybuf);
    gemm_bt<1><<<dim3(NE / 128, MM / 128), 256, 0, stream>>>(ybuf, Wpt, b_proj, out, nullptr, nullptr,
                                                             MM, NE, NE);
}

// Round 9
// 288.564 us; speedup vs baseline: 1.2022x; 1.0372x over previous
//
#include <hip/hip_runtime.h>
#include <hip/hip_bf16.h>

// ---- constants for this problem ----
#define BB 4
#define TT 2048
#define C_IN 1152
#define NE 1024
#define NH 16
#define HD 64
#define MM (BB*TT)          // 8192
#define N_QKV (3*NE)        // 3072

typedef __attribute__((ext_vector_type(8))) short s16x8;
typedef __attribute__((ext_vector_type(4))) short s16x4;
typedef __attribute__((ext_vector_type(4))) float f32x4;

static __device__ __forceinline__ unsigned short f2bf(float x) {
    unsigned int u = __float_as_uint(x);
    unsigned int r = (u + 0x7fffu + ((u >> 16) & 1u)) >> 16;
    return (unsigned short)r;
}

// async global->LDS, 16 B per lane. LDS dest = wave-uniform base + lane*16.
static __device__ __forceinline__ void async16(const void* g, void* l) {
    __builtin_amdgcn_global_load_lds((const __attribute__((address_space(1))) void*)g,
                                     (__attribute__((address_space(3))) void*)l, 16, 0, 0);
}

// ---------------- LayerNorm: x fp32 [M][C_IN] -> h bf16 [M][C_IN] ----------------
// Round-9: float4 loads, values kept in registers (no second read), bf16x4 stores.
__global__ __launch_bounds__(256) void ln_kernel(const float* __restrict__ x,
                                                 const float* __restrict__ w,
                                                 const float* __restrict__ b,
                                                 unsigned short* __restrict__ h) {
    const int row = blockIdx.x;
    const int tid = threadIdx.x;
    const float4* xr = (const float4*)(x + (size_t)row * C_IN);   // 288 float4/row
    const float4 a0 = xr[tid];
    float4 a1 = make_float4(0.f, 0.f, 0.f, 0.f);
    if (tid < 32) a1 = xr[256 + tid];
    float s  = a0.x + a0.y + a0.z + a0.w + a1.x + a1.y + a1.z + a1.w;
    float sq = a0.x*a0.x + a0.y*a0.y + a0.z*a0.z + a0.w*a0.w
             + a1.x*a1.x + a1.y*a1.y + a1.z*a1.z + a1.w*a1.w;
    for (int off = 1; off < 64; off <<= 1) {
        s  += __shfl_xor(s, off, 64);
        sq += __shfl_xor(sq, off, 64);
    }
    __shared__ float red[2][4];
    const int wid = tid >> 6, lane = tid & 63;
    if (lane == 0) { red[0][wid] = s; red[1][wid] = sq; }
    __syncthreads();
    s  = red[0][0] + red[0][1] + red[0][2] + red[0][3];
    sq = red[1][0] + red[1][1] + red[1][2] + red[1][3];
    const float mu  = s * (1.f / C_IN);
    const float var = sq * (1.f / C_IN) - mu * mu;
    const float rs  = rsqrtf(var + 1e-5f);
    const float4* w4 = (const float4*)w;
    const float4* b4 = (const float4*)b;
    unsigned short* hr = h + (size_t)row * C_IN;
    {
        const float4 wv = w4[tid], bv = b4[tid];
        s16x4 o;
        o[0] = (short)f2bf((a0.x - mu) * rs * wv.x + bv.x);
        o[1] = (short)f2bf((a0.y - mu) * rs * wv.y + bv.y);
        o[2] = (short)f2bf((a0.z - mu) * rs * wv.z + bv.z);
        o[3] = (short)f2bf((a0.w - mu) * rs * wv.w + bv.w);
        *(s16x4*)(hr + tid * 4) = o;
    }
    if (tid < 32) {
        const float4 wv = w4[256 + tid], bv = b4[256 + tid];
        s16x4 o;
        o[0] = (short)f2bf((a1.x - mu) * rs * wv.x + bv.x);
        o[1] = (short)f2bf((a1.y - mu) * rs * wv.y + bv.y);
        o[2] = (short)f2bf((a1.z - mu) * rs * wv.z + bv.z);
        o[3] = (short)f2bf((a1.w - mu) * rs * wv.w + bv.w);
        *(s16x4*)(hr + (256 + tid) * 4) = o;
    }
}

// ------------- transpose+cast: in fp32 [K][N] -> out bf16 [N][K] -------------
__global__ __launch_bounds__(256) void transpose_cast(const float* __restrict__ in,
                                                      unsigned short* __restrict__ out,
                                                      int K, int N) {
    __shared__ float tile[32][33];
    const int n0 = blockIdx.x * 32, k0 = blockIdx.y * 32;
    const int tx = threadIdx.x & 31, ty = threadIdx.x >> 5;   // 32 x 8
    for (int i = ty; i < 32; i += 8)
        tile[i][tx] = in[(size_t)(k0 + i) * N + n0 + tx];
    __syncthreads();
    for (int i = ty; i < 32; i += 8)
        out[(size_t)(n0 + i) * K + k0 + tx] = f2bf(tile[tx][i]);
}

#define ATT_SC 0.18033688011112042f   /* (1/8) * log2(e) */

// ------------- GEMM: A bf16 [M][K] x Bt bf16 [N][K] + bias -> epilogue -------------
// Round-8 proven K-loop: BK=64, XOR-swizzled 128-B LDS rows (stage source lanes
// 8-per-row within a 128-B window; read chunk q of row r at LDS[r][q ^ (r&7)]).
// Round-9:
//  - MODE 0 work order: 2D sub-tiled XCD-local mapping (4m x 8n sub-tiles;
//    A 1.2MB + B 2.4MB = 3.6MB fits the 4MB per-XCD L2). The old row-major
//    chunk swept all 7MB of B per m-row -> ~56MB L2-fill per XCD from L3.
//  - MODE 0 epilogue: single-stage [128][EP_STRIDE] (2 barriers, was 8).
// MODE 1 keeps the plain T1 swizzle (its B = 2MB fits L2) + 2-pass fp32 epilogue.
#define EP_STRIDE 136   /* ushort; 272 B rows keep 16 B alignment for b128 */
template <int MODE>
__global__ __launch_bounds__(256) void gemm_bt(const unsigned short* __restrict__ A,
                                               const unsigned short* __restrict__ Bt,
                                               const float* __restrict__ bias,
                                               void* __restrict__ outp,
                                               unsigned short* __restrict__ kb,
                                               unsigned short* __restrict__ vt,
                                               int M, int N, int K) {
    __shared__ unsigned short smem[32768];   // 64 KB: [2 buf][ A 8192 | B 8192 ]
    const int tid = threadIdx.x;
    const int wid = tid >> 6, lane = tid & 63;
    const int wm = wid >> 1, wn = wid & 1;
    const int quad = lane >> 4, l16 = lane & 15;

    int m0, n0;
    if (MODE == 0) {
        // 2D sub-tiled XCD-local order: grid (24,64)=1536, 192 wg per XCD.
        // Sub-tile = 4m x 8n (32 wg); ng inner so A-group stays L2-hot.
        const int bid = blockIdx.y * gridDim.x + blockIdx.x;
        const int xcd = bid & 7;
        const int k   = bid >> 3;          // 0..191
        const int mg  = k / 96;            // 0..1
        const int r1  = k % 96;
        const int ng  = r1 / 32;           // 0..2
        const int rr  = r1 % 32;
        m0 = (xcd * 8 + mg * 4 + (rr & 3)) * 128;
        n0 = (ng * 8 + (rr >> 2)) * 128;
    } else {
        // T1 bijective XCD-chunked swizzle (nwg % 8 == 0)
        const int gx  = gridDim.x;
        const int nwg = gx * gridDim.y;
        const int bid = blockIdx.y * gx + blockIdx.x;
        const int wg  = (bid & 7) * (nwg >> 3) + (bid >> 3);
        m0 = (wg / gx) * 128; n0 = (wg % gx) * 128;
    }

    // staging: wave wid covers rows wid*32 + j*8 + rl (j=0..3); 8 lanes per row,
    // chunk sc XOR'd by row&7 (within the row's 128-B window -> coalesced).
    const int rl = lane >> 3;                     // 0..7
    const int sc = (lane & 7) ^ rl;               // stored chunk index
    const unsigned short* gA = A  + (size_t)(m0 + wid * 32 + rl) * K + sc * 8;
    const unsigned short* gB = Bt + (size_t)(n0 + wid * 32 + rl) * K + sc * 8;

    f32x4 acc[4][4] = {};
    const int nk = K >> 6;

    // per-thread read chunk indices (inverse XOR): row&7 == l16&7 for all frags
    const int sc0 = (quad ^ (l16 & 7)) * 8;
    const int sc1 = ((4 + quad) ^ (l16 & 7)) * 8;

#define STAGE(KT, BUF)                                                          \
    {                                                                           \
        const unsigned short* a_ = gA + (KT) * 64;                              \
        const unsigned short* b_ = gB + (KT) * 64;                              \
        unsigned short* sa_ = &smem[(BUF) * 16384 + wid * 2048];                \
        unsigned short* sb_ = &smem[(BUF) * 16384 + 8192 + wid * 2048];         \
        _Pragma("unroll")                                                       \
        for (int j = 0; j < 4; j++) {                                           \
            async16(a_ + (size_t)(j * 8) * K, sa_ + j * 512);                   \
            async16(b_ + (size_t)(j * 8) * K, sb_ + j * 512);                   \
        }                                                                       \
    }

    STAGE(0, 0);

    for (int kt = 0; kt < nk; kt++) {
        __syncthreads();
        const int cur = kt & 1;
        if (kt + 1 < nk) STAGE(kt + 1, cur ^ 1);

        const unsigned short* As_ = &smem[cur * 16384];
        const unsigned short* Bs_ = &smem[cur * 16384 + 8192];
        #pragma unroll
        for (int h = 0; h < 2; h++) {
            const int sch = h ? sc1 : sc0;
            s16x8 af[4], bfb[4];
            #pragma unroll
            for (int mi = 0; mi < 4; mi++)
                af[mi] = *(const s16x8*)&As_[(wm * 64 + mi * 16 + l16) * 64 + sch];
            #pragma unroll
            for (int ni = 0; ni < 4; ni++)
                bfb[ni] = *(const s16x8*)&Bs_[(wn * 64 + ni * 16 + l16) * 64 + sch];
            #pragma unroll
            for (int mi = 0; mi < 4; mi++)
                #pragma unroll
                for (int ni = 0; ni < 4; ni++)
                    acc[mi][ni] = __builtin_amdgcn_mfma_f32_16x16x32_bf16(af[mi], bfb[ni], acc[mi][ni], 0, 0, 0);
        }
    }
#undef STAGE

    // bias into registers (+ ATT_SC pre-scale for the q third)
    const int which0 = n0 >> 10;
    const float sc_ = (MODE == 0 && which0 == 0) ? ATT_SC : 1.0f;
    for (int ni = 0; ni < 4; ni++) {
        const float bv = bias[n0 + wn * 64 + ni * 16 + l16];
        for (int mi = 0; mi < 4; mi++)
            for (int r = 0; r < 4; r++)
                acc[mi][ni][r] = (acc[mi][ni][r] + bv) * sc_;
    }

    if (MODE == 1) {
        // LDS-routed coalesced fp32 epilogue: 2 passes of 64 rows.
        float* Tf = (float*)smem;
        float* out = (float*)outp;
        for (int p = 0; p < 2; p++) {
            __syncthreads();
            if (wm == p) {
                for (int mi = 0; mi < 4; mi++)
                    for (int ni = 0; ni < 4; ni++) {
                        const int col = wn * 64 + ni * 16 + l16;
                        for (int r = 0; r < 4; r++)
                            Tf[(mi * 16 + quad * 4 + r) * 128 + col] = acc[mi][ni][r];
                    }
            }
            __syncthreads();
            const int rlo = tid >> 5;         // 0..7
            const int c4 = (tid & 31) * 4;    // f32 col, 16B-aligned
            for (int rr2 = rlo; rr2 < 64; rr2 += 8) {
                *(float4*)&out[(size_t)(m0 + p * 64 + rr2) * N + n0 + c4] =
                    *(const float4*)&Tf[rr2 * 128 + c4];
            }
        }
        return;
    }

    // ---- MODE 0: single-stage LDS-routed epilogue (T [128][EP_STRIDE] = 34.8 KB) ----
    const int which = n0 >> 10;                    // 0=q 1=k 2=v (uniform)
    const int bb = m0 >> 11;
    const int mloc = m0 & 2047;                    // batch-local time base
    unsigned short* T = smem;

    __syncthreads();
    if (which < 2) {
        // T rows = m_local (0..127), cols = n_local (0..127)
        for (int mi = 0; mi < 4; mi++)
            for (int ni = 0; ni < 4; ni++) {
                const int nl = wn * 64 + ni * 16 + l16;
                for (int r = 0; r < 4; r++)
                    T[(wm * 64 + mi * 16 + quad * 4 + r) * EP_STRIDE + nl] = f2bf(acc[mi][ni][r]);
            }
    } else {
        // T rows = n_local (0..127), cols = m_local (0..127)
        for (int mi = 0; mi < 4; mi++)
            for (int ni = 0; ni < 4; ni++) {
                const int nlh = wn * 64 + ni * 16 + l16;
                const int mlb = wm * 64 + mi * 16 + quad * 4;
                for (int r = 0; r < 4; r += 2) {
                    const unsigned int pk = (unsigned int)f2bf(acc[mi][ni][r]) |
                                            ((unsigned int)f2bf(acc[mi][ni][r + 1]) << 16);
                    *(unsigned int*)&T[nlh * EP_STRIDE + mlb + r] = pk;
                }
            }
    }
    __syncthreads();

    if (which < 2) {
        unsigned short* qk = (which == 0) ? (unsigned short*)outp : kb;
        const int ml = tid >> 2, c = tid & 3;
        const int nl0 = c * 32;
        const int hh = ((n0 & 1023) >> 6) + (nl0 >> 6);
        const int d0 = nl0 & 63;
        for (int half = 0; half < 2; half++) {
            const int row = half * 64 + ml;
            const int t = mloc + row;
            unsigned short* dst = qk + ((size_t)(bb * 16 + hh) * TT + t) * HD + d0;
            const unsigned short* src = &T[row * EP_STRIDE + nl0];
            for (int u = 0; u < 4; u++)
                *(s16x8*)(dst + u * 8) = *(const s16x8*)(src + u * 8);
        }
    } else {
        const int nlh = tid >> 2, c = tid & 3;
        const int hb = (n0 - 2048) >> 6;
        for (int half = 0; half < 2; half++) {
            const int row = half * 64 + nlh;
            unsigned short* dst = vt + ((size_t)(bb * 16 + hb + half) * HD + nlh) * TT + mloc + c * 32;
            const unsigned short* src = &T[row * EP_STRIDE + c * 32];
            for (int u = 0; u < 4; u++)
                *(s16x8*)(dst + u * 8) = *(const s16x8*)(src + u * 8);
        }
    }
}

// ------------- flash attention: S^T trick + ones-MFMA row sums -------------
// Round-8 proven version (round-0 schedule + XOR-swizzled K/V + diag-hoisted mask)
// + round-9: T5 setprio(1) around the rowsum+PV MFMA cluster (m191: attn +4-7%).
#define PST 72                         /* shorts; 144 B rows, 16B-aligned */

__global__ __launch_bounds__(256) void attn_kernel(const unsigned short* __restrict__ qb,
                                                   const unsigned short* __restrict__ kb,
                                                   const unsigned short* __restrict__ vt,
                                                   unsigned short* __restrict__ yb) {
    __shared__ unsigned short Ks[2][64 * 64];
    __shared__ unsigned short Vs[2][64 * 64];
    __shared__ unsigned short Ps[4][2 * 16 * PST];   // per-wave, per-mf [16 q][PST]
    const int tid = threadIdx.x, wid = tid >> 6, lane = tid & 63;
    const int quad = lane >> 4, l16 = lane & 15;
    const int bh = blockIdx.x & 63;
    const int qblk = 15 - (blockIdx.x >> 6);         // longest-first (LPT packing)

    const unsigned short* qh = qb + (size_t)bh * TT * HD;
    const unsigned short* kh = kb + (size_t)bh * TT * HD;
    const unsigned short* vh = vt + (size_t)bh * HD * TT;
    unsigned short* ps = Ps[wid];

    const int q0w = qblk * 128 + wid * 32;           // this wave's 32 q-rows
    s16x8 aq[2][2];
    #pragma unroll
    for (int mf = 0; mf < 2; mf++) {
        aq[mf][0] = *(const s16x8*)&qh[(size_t)(q0w + mf * 16 + l16) * HD + quad * 8];
        aq[mf][1] = *(const s16x8*)&qh[(size_t)(q0w + mf * 16 + l16) * HD + 32 + quad * 8];
    }
    // ones B-frag (bf16 1.0 = 0x3F80)
    s16x8 onesf;
    #pragma unroll
    for (int i = 0; i < 8; i++) onesf[i] = (short)0x3F80;

    f32x4 yacc[2][4] = {};
    f32x4 lacc[2] = {};                              // row-sum accumulators
    const int ntiles = 2 * qblk + 2;                 // always even

    // staging: row r = wid*16 + {0,8} + rl, chunk cc XOR-swizzled; pointers bumped
    const int rl = lane >> 3;
    const int cc = (lane & 7) ^ (rl & 7);
    const unsigned short* kp0 = kh + (size_t)(wid * 16 + rl) * HD + cc * 8;
    const unsigned short* kp1 = kh + (size_t)(wid * 16 + 8 + rl) * HD + cc * 8;
    const unsigned short* vp0 = vh + (size_t)(wid * 16 + rl) * TT + cc * 8;
    const unsigned short* vp1 = vh + (size_t)(wid * 16 + 8 + rl) * TT + cc * 8;
    const int ldsK0 = wid * 16 * 64, ldsK1 = (wid * 16 + 8) * 64;

    // prologue: stage tile 0 into buffer 0; bump to tile 1
    async16(kp0, &Ks[0][ldsK0]);  async16(kp1, &Ks[0][ldsK1]);
    async16(vp0, &Vs[0][ldsK0]);  async16(vp1, &Vs[0][ldsK1]);
    kp0 += 64 * HD; kp1 += 64 * HD; vp0 += 64; vp1 += 64;

    const int p0s = quad ^ (l16 & 7);
    const int p1s = (4 + quad) ^ (l16 & 7);

#define ATT_STEP(CUR, TT_)                                                              \
    {                                                                                   \
        __syncthreads();                                                                \
        if ((TT_) + 1 < ntiles) {                                                       \
            async16(kp0, &Ks[(CUR) ^ 1][ldsK0]);  async16(kp1, &Ks[(CUR) ^ 1][ldsK1]);  \
            async16(vp0, &Vs[(CUR) ^ 1][ldsK0]);  async16(vp1, &Vs[(CUR) ^ 1][ldsK1]);  \
            kp0 += 64 * HD; kp1 += 64 * HD; vp0 += 64; vp1 += 64;                       \
        }                                                                               \
        const int tk0 = (TT_) * 64;                                                     \
        if (tk0 <= q0w + 31) {                                                          \
            const unsigned short* Kc = Ks[CUR];                                         \
            const unsigned short* Vc = Vs[CUR];                                         \
            s16x8 kf[4][2], vf[4][2];                                                   \
            _Pragma("unroll")                                                           \
            for (int nj = 0; nj < 4; nj++) {                                            \
                kf[nj][0] = *(const s16x8*)&Kc[(nj * 16 + l16) * 64 + p0s * 8];         \
                kf[nj][1] = *(const s16x8*)&Kc[(nj * 16 + l16) * 64 + p1s * 8];         \
            }                                                                           \
            _Pragma("unroll")                                                           \
            for (int ni = 0; ni < 4; ni++) {                                            \
                vf[ni][0] = *(const s16x8*)&Vc[(ni * 16 + l16) * 64 + p0s * 8];         \
                vf[ni][1] = *(const s16x8*)&Vc[(ni * 16 + l16) * 64 + p1s * 8];         \
            }                                                                           \
            _Pragma("unroll")                                                           \
            for (int mf = 0; mf < 2; mf++) {                                            \
                const int f0 = q0w + mf * 16;                                           \
                if (tk0 > f0 + 15) continue;                                            \
                unsigned short* pm = ps + mf * (16 * PST);                              \
                const int qg = f0 + l16;                                                \
                f32x4 st[4];                                                            \
                _Pragma("unroll")                                                       \
                for (int nj = 0; nj < 4; nj++) {                                        \
                    f32x4 z = {};                                                       \
                    z = __builtin_amdgcn_mfma_f32_16x16x32_bf16(kf[nj][0], aq[mf][0], z, 0, 0, 0); \
                    z = __builtin_amdgcn_mfma_f32_16x16x32_bf16(kf[nj][1], aq[mf][1], z, 0, 0, 0); \
                    st[nj] = z;                                                         \
                }                                                                       \
                const bool diag = (tk0 + 64 > f0);                                      \
                float pv[4][4];                                                         \
                _Pragma("unroll")                                                       \
                for (int nj = 0; nj < 4; nj++)                                          \
                    _Pragma("unroll")                                                   \
                    for (int r = 0; r < 4; r++)                                         \
                        pv[nj][r] = exp2f(st[nj][r]);                                   \
                if (diag) {                                                             \
                    _Pragma("unroll")                                                   \
                    for (int nj = 0; nj < 4; nj++) {                                    \
                        const int keyb = tk0 + nj * 16 + quad * 4;                      \
                        _Pragma("unroll")                                               \
                        for (int r = 0; r < 4; r++)                                     \
                            if (keyb + r > qg) pv[nj][r] = 0.f;                         \
                    }                                                                   \
                }                                                                       \
                _Pragma("unroll")                                                       \
                for (int nj = 0; nj < 4; nj++) {                                        \
                    const unsigned int pk0 = __builtin_amdgcn_perm(                     \
                        __float_as_uint(pv[nj][1]), __float_as_uint(pv[nj][0]), 0x07060302u); \
                    const unsigned int pk1 = __builtin_amdgcn_perm(                     \
                        __float_as_uint(pv[nj][3]), __float_as_uint(pv[nj][2]), 0x07060302u); \
                    *(uint2*)&pm[l16 * PST + nj * 16 + quad * 4] = make_uint2(pk0, pk1);\
                }                                                                       \
                __asm volatile("s_waitcnt lgkmcnt(0)" ::: "memory");                    \
                __builtin_amdgcn_s_setprio(1);                                          \
                const s16x8 ap0 = *(const s16x8*)&pm[l16 * PST + quad * 8];             \
                const s16x8 ap1 = *(const s16x8*)&pm[l16 * PST + 32 + quad * 8];        \
                lacc[mf] = __builtin_amdgcn_mfma_f32_16x16x32_bf16(ap0, onesf, lacc[mf], 0, 0, 0); \
                lacc[mf] = __builtin_amdgcn_mfma_f32_16x16x32_bf16(ap1, onesf, lacc[mf], 0, 0, 0); \
                _Pragma("unroll")                                                       \
                for (int ni = 0; ni < 4; ni++) {                                        \
                    yacc[mf][ni] = __builtin_amdgcn_mfma_f32_16x16x32_bf16(ap0, vf[ni][0], yacc[mf][ni], 0, 0, 0); \
                    yacc[mf][ni] = __builtin_amdgcn_mfma_f32_16x16x32_bf16(ap1, vf[ni][1], yacc[mf][ni], 0, 0, 0); \
                }                                                                       \
                __builtin_amdgcn_s_setprio(0);                                          \
            }                                                                           \
        }                                                                               \
    }

    for (int t = 0; t < ntiles; t += 2) {
        ATT_STEP(0, t);
        ATT_STEP(1, t + 1);
    }
#undef ATT_STEP

    // epilogue: lacc[mf][r] is the denominator for q = f0 + quad*4 + r — the exact
    // same (quad,r) indexing as yacc. No cross-lane reduction needed.
    const int bbi = bh >> 4, hh = bh & 15;
    #pragma unroll
    for (int mf = 0; mf < 2; mf++) {
        float linv[4];
        #pragma unroll
        for (int r = 0; r < 4; r++)
            linv[r] = 1.0f / lacc[mf][r];
        #pragma unroll
        for (int ni = 0; ni < 4; ni++)
            #pragma unroll
            for (int r = 0; r < 4; r++) {
                const int trow = q0w + mf * 16 + quad * 4 + r;
                yb[((size_t)bbi * TT + trow) * NE + hh * HD + ni * 16 + l16] =
                    f2bf(yacc[mf][ni][r] * linv[r]);
            }
    }
}

extern "C" void kernel_launch(void* const* d_in, const int* in_sizes, int n_in,
                              void* d_out, int out_size, void* d_ws, size_t ws_size,
                              hipStream_t stream) {
    const float* x      = (const float*)d_in[0];
    const float* ln_w   = (const float*)d_in[1];
    const float* ln_b   = (const float*)d_in[2];
    const float* W_attn = (const float*)d_in[3];
    const float* b_attn = (const float*)d_in[4];
    const float* W_proj = (const float*)d_in[5];
    const float* b_proj = (const float*)d_in[6];
    float* out = (float*)d_out;

    char* ws = (char*)d_ws;
    unsigned short* h    = (unsigned short*)ws;  ws += (size_t)MM * C_IN * 2;
    unsigned short* Wat  = (unsigned short*)ws;  ws += (size_t)N_QKV * C_IN * 2;
    unsigned short* Wpt  = (unsigned short*)ws;  ws += (size_t)NE * NE * 2;
    unsigned short* qbuf = (unsigned short*)ws;  ws += (size_t)MM * NE * 2;
    unsigned short* kbuf = (unsigned short*)ws;  ws += (size_t)MM * NE * 2;
    unsigned short* vtbf = (unsigned short*)ws;  ws += (size_t)MM * NE * 2;
    unsigned short* ybuf = (unsigned short*)ws;  ws += (size_t)MM * NE * 2;

    ln_kernel<<<MM, 256, 0, stream>>>(x, ln_w, ln_b, h);
    transpose_cast<<<dim3(N_QKV / 32, C_IN / 32), 256, 0, stream>>>(W_attn, Wat, C_IN, N_QKV);
    transpose_cast<<<dim3(NE / 32, NE / 32), 256, 0, stream>>>(W_proj, Wpt, NE, NE);
    gemm_bt<0><<<dim3(N_QKV / 128, MM / 128), 256, 0, stream>>>(h, Wat, b_attn, qbuf, kbuf, vtbf,
                                                                MM, N_QKV, C_IN);
    attn_kernel<<<64 * 16, 256, 0, stream>>>(qbuf, kbuf, vtbf, ybuf);
    gemm_bt<1><<<dim3(NE / 128, MM / 128), 256, 0, stream>>>(ybuf, Wpt, b_proj, out, nullptr, nullptr,
                                                             MM, NE, NE);
}

// Round 10
// 287.580 us; speedup vs baseline: 1.2063x; 1.0034x over previous
//
#include <hip/hip_runtime.h>
#include <hip/hip_bf16.h>

// ---- constants for this problem ----
#define BB 4
#define TT 2048
#define C_IN 1152
#define NE 1024
#define NH 16
#define HD 64
#define MM (BB*TT)          // 8192
#define N_QKV (3*NE)        // 3072

typedef __attribute__((ext_vector_type(8))) short s16x8;
typedef __attribute__((ext_vector_type(4))) short s16x4;
typedef __attribute__((ext_vector_type(4))) float f32x4;

static __device__ __forceinline__ unsigned short f2bf(float x) {
    unsigned int u = __float_as_uint(x);
    unsigned int r = (u + 0x7fffu + ((u >> 16) & 1u)) >> 16;
    return (unsigned short)r;
}

// async global->LDS, 16 B per lane. LDS dest = wave-uniform base + lane*16.
static __device__ __forceinline__ void async16(const void* g, void* l) {
    __builtin_amdgcn_global_load_lds((const __attribute__((address_space(1))) void*)g,
                                     (__attribute__((address_space(3))) void*)l, 16, 0, 0);
}

// ---- prep kernel: LN (blocks 0..MM-1) + both weight transposes (rest) ----
// Fuses 3 launches into 1. Branches are whole-block uniform.
#define TCA_BLOCKS ((N_QKV / 32) * (C_IN / 32))   /* 3456 */
#define TCP_BLOCKS ((NE / 32) * (NE / 32))        /* 1024 */
__global__ __launch_bounds__(256) void prep_kernel(const float* __restrict__ x,
                                                   const float* __restrict__ lw,
                                                   const float* __restrict__ lb,
                                                   unsigned short* __restrict__ h,
                                                   const float* __restrict__ Wa,
                                                   unsigned short* __restrict__ Wat,
                                                   const float* __restrict__ Wp,
                                                   unsigned short* __restrict__ Wpt) {
    __shared__ float tile[32][33];
    __shared__ float red[2][4];
    const int bid = blockIdx.x;
    const int tid = threadIdx.x;

    if (bid < MM) {
        // ---- LayerNorm row (float4 loads, registers kept, bf16x4 stores) ----
        const float4* xr = (const float4*)(x + (size_t)bid * C_IN);   // 288 float4
        const float4 a0 = xr[tid];
        float4 a1 = make_float4(0.f, 0.f, 0.f, 0.f);
        if (tid < 32) a1 = xr[256 + tid];
        float s  = a0.x + a0.y + a0.z + a0.w + a1.x + a1.y + a1.z + a1.w;
        float sq = a0.x*a0.x + a0.y*a0.y + a0.z*a0.z + a0.w*a0.w
                 + a1.x*a1.x + a1.y*a1.y + a1.z*a1.z + a1.w*a1.w;
        for (int off = 1; off < 64; off <<= 1) {
            s  += __shfl_xor(s, off, 64);
            sq += __shfl_xor(sq, off, 64);
        }
        const int wid = tid >> 6, lane = tid & 63;
        if (lane == 0) { red[0][wid] = s; red[1][wid] = sq; }
        __syncthreads();
        s  = red[0][0] + red[0][1] + red[0][2] + red[0][3];
        sq = red[1][0] + red[1][1] + red[1][2] + red[1][3];
        const float mu  = s * (1.f / C_IN);
        const float var = sq * (1.f / C_IN) - mu * mu;
        const float rs  = rsqrtf(var + 1e-5f);
        const float4* w4 = (const float4*)lw;
        const float4* b4 = (const float4*)lb;
        unsigned short* hr = h + (size_t)bid * C_IN;
        {
            const float4 wv = w4[tid], bv = b4[tid];
            s16x4 o;
            o[0] = (short)f2bf((a0.x - mu) * rs * wv.x + bv.x);
            o[1] = (short)f2bf((a0.y - mu) * rs * wv.y + bv.y);
            o[2] = (short)f2bf((a0.z - mu) * rs * wv.z + bv.z);
            o[3] = (short)f2bf((a0.w - mu) * rs * wv.w + bv.w);
            *(s16x4*)(hr + tid * 4) = o;
        }
        if (tid < 32) {
            const float4 wv = w4[256 + tid], bv = b4[256 + tid];
            s16x4 o;
            o[0] = (short)f2bf((a1.x - mu) * rs * wv.x + bv.x);
            o[1] = (short)f2bf((a1.y - mu) * rs * wv.y + bv.y);
            o[2] = (short)f2bf((a1.z - mu) * rs * wv.z + bv.z);
            o[3] = (short)f2bf((a1.w - mu) * rs * wv.w + bv.w);
            *(s16x4*)(hr + (256 + tid) * 4) = o;
        }
        return;
    }

    // ---- transpose+cast tile ----
    const float* in; unsigned short* out; int K, N, n0, k0;
    if (bid < MM + TCA_BLOCKS) {
        const int idx = bid - MM;
        in = Wa; out = Wat; K = C_IN; N = N_QKV;
        n0 = (idx % (N_QKV / 32)) * 32; k0 = (idx / (N_QKV / 32)) * 32;
    } else {
        const int idx = bid - MM - TCA_BLOCKS;
        in = Wp; out = Wpt; K = NE; N = NE;
        n0 = (idx % (NE / 32)) * 32; k0 = (idx / (NE / 32)) * 32;
    }
    const int tx = tid & 31, ty = tid >> 5;   // 32 x 8
    for (int i = ty; i < 32; i += 8)
        tile[i][tx] = in[(size_t)(k0 + i) * N + n0 + tx];
    __syncthreads();
    for (int i = ty; i < 32; i += 8)
        out[(size_t)(n0 + i) * K + k0 + tx] = f2bf(tile[tx][i]);
}

#define ATT_SC 0.18033688011112042f   /* (1/8) * log2(e) */

// ------------- GEMM: A bf16 [M][K] x Bt bf16 [N][K] + bias -> epilogue -------------
// Round-8 proven K-loop: BK=64, XOR-swizzled 128-B LDS rows.
// Round-9: MODE-0 L2-local 2D sub-tiled work order; single-stage MODE-0 epilogue.
#define EP_STRIDE 136   /* ushort; 272 B rows keep 16 B alignment for b128 */
template <int MODE>
__global__ __launch_bounds__(256) void gemm_bt(const unsigned short* __restrict__ A,
                                               const unsigned short* __restrict__ Bt,
                                               const float* __restrict__ bias,
                                               void* __restrict__ outp,
                                               unsigned short* __restrict__ kb,
                                               unsigned short* __restrict__ vt,
                                               int M, int N, int K) {
    __shared__ unsigned short smem[32768];   // 64 KB: [2 buf][ A 8192 | B 8192 ]
    const int tid = threadIdx.x;
    const int wid = tid >> 6, lane = tid & 63;
    const int wm = wid >> 1, wn = wid & 1;
    const int quad = lane >> 4, l16 = lane & 15;

    int m0, n0;
    if (MODE == 0) {
        // 2D sub-tiled XCD-local order: grid (24,64)=1536, 192 wg per XCD.
        const int bid = blockIdx.y * gridDim.x + blockIdx.x;
        const int xcd = bid & 7;
        const int k   = bid >> 3;          // 0..191
        const int mg  = k / 96;            // 0..1
        const int r1  = k % 96;
        const int ng  = r1 / 32;           // 0..2
        const int rr  = r1 % 32;
        m0 = (xcd * 8 + mg * 4 + (rr & 3)) * 128;
        n0 = (ng * 8 + (rr >> 2)) * 128;
    } else {
        // T1 bijective XCD-chunked swizzle (nwg % 8 == 0)
        const int gx  = gridDim.x;
        const int nwg = gx * gridDim.y;
        const int bid = blockIdx.y * gx + blockIdx.x;
        const int wg  = (bid & 7) * (nwg >> 3) + (bid >> 3);
        m0 = (wg / gx) * 128; n0 = (wg % gx) * 128;
    }

    const int rl = lane >> 3;                     // 0..7
    const int sc = (lane & 7) ^ rl;               // stored chunk index
    const unsigned short* gA = A  + (size_t)(m0 + wid * 32 + rl) * K + sc * 8;
    const unsigned short* gB = Bt + (size_t)(n0 + wid * 32 + rl) * K + sc * 8;

    f32x4 acc[4][4] = {};
    const int nk = K >> 6;

    const int sc0 = (quad ^ (l16 & 7)) * 8;
    const int sc1 = ((4 + quad) ^ (l16 & 7)) * 8;

#define STAGE(KT, BUF)                                                          \
    {                                                                           \
        const unsigned short* a_ = gA + (KT) * 64;                              \
        const unsigned short* b_ = gB + (KT) * 64;                              \
        unsigned short* sa_ = &smem[(BUF) * 16384 + wid * 2048];                \
        unsigned short* sb_ = &smem[(BUF) * 16384 + 8192 + wid * 2048];         \
        _Pragma("unroll")                                                       \
        for (int j = 0; j < 4; j++) {                                           \
            async16(a_ + (size_t)(j * 8) * K, sa_ + j * 512);                   \
            async16(b_ + (size_t)(j * 8) * K, sb_ + j * 512);                   \
        }                                                                       \
    }

    STAGE(0, 0);

    for (int kt = 0; kt < nk; kt++) {
        __syncthreads();
        const int cur = kt & 1;
        if (kt + 1 < nk) STAGE(kt + 1, cur ^ 1);

        const unsigned short* As_ = &smem[cur * 16384];
        const unsigned short* Bs_ = &smem[cur * 16384 + 8192];
        #pragma unroll
        for (int h = 0; h < 2; h++) {
            const int sch = h ? sc1 : sc0;
            s16x8 af[4], bfb[4];
            #pragma unroll
            for (int mi = 0; mi < 4; mi++)
                af[mi] = *(const s16x8*)&As_[(wm * 64 + mi * 16 + l16) * 64 + sch];
            #pragma unroll
            for (int ni = 0; ni < 4; ni++)
                bfb[ni] = *(const s16x8*)&Bs_[(wn * 64 + ni * 16 + l16) * 64 + sch];
            #pragma unroll
            for (int mi = 0; mi < 4; mi++)
                #pragma unroll
                for (int ni = 0; ni < 4; ni++)
                    acc[mi][ni] = __builtin_amdgcn_mfma_f32_16x16x32_bf16(af[mi], bfb[ni], acc[mi][ni], 0, 0, 0);
        }
    }
#undef STAGE

    const int which0 = n0 >> 10;
    const float sc_ = (MODE == 0 && which0 == 0) ? ATT_SC : 1.0f;
    for (int ni = 0; ni < 4; ni++) {
        const float bv = bias[n0 + wn * 64 + ni * 16 + l16];
        for (int mi = 0; mi < 4; mi++)
            for (int r = 0; r < 4; r++)
                acc[mi][ni][r] = (acc[mi][ni][r] + bv) * sc_;
    }

    if (MODE == 1) {
        float* Tf = (float*)smem;
        float* out = (float*)outp;
        for (int p = 0; p < 2; p++) {
            __syncthreads();
            if (wm == p) {
                for (int mi = 0; mi < 4; mi++)
                    for (int ni = 0; ni < 4; ni++) {
                        const int col = wn * 64 + ni * 16 + l16;
                        for (int r = 0; r < 4; r++)
                            Tf[(mi * 16 + quad * 4 + r) * 128 + col] = acc[mi][ni][r];
                    }
            }
            __syncthreads();
            const int rlo = tid >> 5;
            const int c4 = (tid & 31) * 4;
            for (int rr2 = rlo; rr2 < 64; rr2 += 8) {
                *(float4*)&out[(size_t)(m0 + p * 64 + rr2) * N + n0 + c4] =
                    *(const float4*)&Tf[rr2 * 128 + c4];
            }
        }
        return;
    }

    // ---- MODE 0: single-stage LDS-routed epilogue (T [128][EP_STRIDE]) ----
    const int which = n0 >> 10;
    const int bb = m0 >> 11;
    const int mloc = m0 & 2047;
    unsigned short* T = smem;

    __syncthreads();
    if (which < 2) {
        for (int mi = 0; mi < 4; mi++)
            for (int ni = 0; ni < 4; ni++) {
                const int nl = wn * 64 + ni * 16 + l16;
                for (int r = 0; r < 4; r++)
                    T[(wm * 64 + mi * 16 + quad * 4 + r) * EP_STRIDE + nl] = f2bf(acc[mi][ni][r]);
            }
    } else {
        for (int mi = 0; mi < 4; mi++)
            for (int ni = 0; ni < 4; ni++) {
                const int nlh = wn * 64 + ni * 16 + l16;
                const int mlb = wm * 64 + mi * 16 + quad * 4;
                for (int r = 0; r < 4; r += 2) {
                    const unsigned int pk = (unsigned int)f2bf(acc[mi][ni][r]) |
                                            ((unsigned int)f2bf(acc[mi][ni][r + 1]) << 16);
                    *(unsigned int*)&T[nlh * EP_STRIDE + mlb + r] = pk;
                }
            }
    }
    __syncthreads();

    if (which < 2) {
        unsigned short* qk = (which == 0) ? (unsigned short*)outp : kb;
        const int ml = tid >> 2, c = tid & 3;
        const int nl0 = c * 32;
        const int hh = ((n0 & 1023) >> 6) + (nl0 >> 6);
        const int d0 = nl0 & 63;
        for (int half = 0; half < 2; half++) {
            const int row = half * 64 + ml;
            const int t = mloc + row;
            unsigned short* dst = qk + ((size_t)(bb * 16 + hh) * TT + t) * HD + d0;
            const unsigned short* src = &T[row * EP_STRIDE + nl0];
            for (int u = 0; u < 4; u++)
                *(s16x8*)(dst + u * 8) = *(const s16x8*)(src + u * 8);
        }
    } else {
        const int nlh = tid >> 2, c = tid & 3;
        const int hb = (n0 - 2048) >> 6;
        for (int half = 0; half < 2; half++) {
            const int row = half * 64 + nlh;
            unsigned short* dst = vt + ((size_t)(bb * 16 + hb + half) * HD + nlh) * TT + mloc + c * 32;
            const unsigned short* src = &T[row * EP_STRIDE + c * 32];
            for (int u = 0; u < 4; u++)
                *(s16x8*)(dst + u * 8) = *(const s16x8*)(src + u * 8);
        }
    }
}

// ------------- flash attention: S^T trick + ones-MFMA row sums -------------
// Round-10: 8-wave blocks (512 thr, 256 q-rows). Same per-wave pipeline
// (XOR-swizzled K/V staging, diag-hoisted mask, setprio'd rowsum+PV), but the
// staged K/V tile now serves 2x the q-rows: 2 async16/wave/step (was 4),
// K/V re-fetch halves, 16 waves/CU residency (2 blocks x 8 waves) for
// cross-wave MFMA/VALU overlap. Block order pairs qblk (7-i) with i so each
// CU's two blocks sum to constant work.
#define PST 72                         /* shorts; 144 B rows, 16B-aligned */

__global__ __launch_bounds__(512) void attn_kernel(const unsigned short* __restrict__ qb,
                                                   const unsigned short* __restrict__ kb,
                                                   const unsigned short* __restrict__ vt,
                                                   unsigned short* __restrict__ yb) {
    __shared__ unsigned short Ks[2][64 * 64];
    __shared__ unsigned short Vs[2][64 * 64];
    __shared__ unsigned short Ps[8][2 * 16 * PST];   // per-wave, per-mf [16 q][PST]
    const int tid = threadIdx.x, wid = tid >> 6, lane = tid & 63;
    const int quad = lane >> 4, l16 = lane & 15;
    const int bh = blockIdx.x & 63;
    const int qidx = blockIdx.x >> 6;                // 0..7
    const int qblk = (qidx < 4) ? (7 - qidx) : (qidx - 4);  // constant-sum pairing

    const unsigned short* qh = qb + (size_t)bh * TT * HD;
    const unsigned short* kh = kb + (size_t)bh * TT * HD;
    const unsigned short* vh = vt + (size_t)bh * HD * TT;
    unsigned short* ps = Ps[wid];

    const int q0w = qblk * 256 + wid * 32;           // this wave's 32 q-rows
    s16x8 aq[2][2];
    #pragma unroll
    for (int mf = 0; mf < 2; mf++) {
        aq[mf][0] = *(const s16x8*)&qh[(size_t)(q0w + mf * 16 + l16) * HD + quad * 8];
        aq[mf][1] = *(const s16x8*)&qh[(size_t)(q0w + mf * 16 + l16) * HD + 32 + quad * 8];
    }
    // ones B-frag (bf16 1.0 = 0x3F80)
    s16x8 onesf;
    #pragma unroll
    for (int i = 0; i < 8; i++) onesf[i] = (short)0x3F80;

    f32x4 yacc[2][4] = {};
    f32x4 lacc[2] = {};                              // row-sum accumulators
    const int ntiles = 4 * qblk + 4;                 // always even

    // staging: wave wid covers rows wid*8 + rl; chunk cc XOR-swizzled
    const int rl = lane >> 3;
    const int cc = (lane & 7) ^ rl;
    const unsigned short* kp0 = kh + (size_t)(wid * 8 + rl) * HD + cc * 8;
    const unsigned short* vp0 = vh + (size_t)(wid * 8 + rl) * TT + cc * 8;
    const int ldsF = wid * 512;                      // 8 rows * 64 shorts

    // prologue: stage tile 0 into buffer 0; bump to tile 1
    async16(kp0, &Ks[0][ldsF]);
    async16(vp0, &Vs[0][ldsF]);
    kp0 += 64 * HD; vp0 += 64;

    const int p0s = quad ^ (l16 & 7);
    const int p1s = (4 + quad) ^ (l16 & 7);

#define ATT_STEP(CUR, TT_)                                                              \
    {                                                                                   \
        __syncthreads();                                                                \
        if ((TT_) + 1 < ntiles) {                                                       \
            async16(kp0, &Ks[(CUR) ^ 1][ldsF]);                                         \
            async16(vp0, &Vs[(CUR) ^ 1][ldsF]);                                         \
            kp0 += 64 * HD; vp0 += 64;                                                  \
        }                                                                               \
        const int tk0 = (TT_) * 64;                                                     \
        if (tk0 <= q0w + 31) {                                                          \
            const unsigned short* Kc = Ks[CUR];                                         \
            const unsigned short* Vc = Vs[CUR];                                         \
            s16x8 kf[4][2], vf[4][2];                                                   \
            _Pragma("unroll")                                                           \
            for (int nj = 0; nj < 4; nj++) {                                            \
                kf[nj][0] = *(const s16x8*)&Kc[(nj * 16 + l16) * 64 + p0s * 8];         \
                kf[nj][1] = *(const s16x8*)&Kc[(nj * 16 + l16) * 64 + p1s * 8];         \
            }                                                                           \
            _Pragma("unroll")                                                           \
            for (int ni = 0; ni < 4; ni++) {                                            \
                vf[ni][0] = *(const s16x8*)&Vc[(ni * 16 + l16) * 64 + p0s * 8];         \
                vf[ni][1] = *(const s16x8*)&Vc[(ni * 16 + l16) * 64 + p1s * 8];         \
            }                                                                           \
            _Pragma("unroll")                                                           \
            for (int mf = 0; mf < 2; mf++) {                                            \
                const int f0 = q0w + mf * 16;                                           \
                if (tk0 > f0 + 15) continue;                                            \
                unsigned short* pm = ps + mf * (16 * PST);                              \
                const int qg = f0 + l16;                                                \
                f32x4 st[4];                                                            \
                _Pragma("unroll")                                                       \
                for (int nj = 0; nj < 4; nj++) {                                        \
                    f32x4 z = {};                                                       \
                    z = __builtin_amdgcn_mfma_f32_16x16x32_bf16(kf[nj][0], aq[mf][0], z, 0, 0, 0); \
                    z = __builtin_amdgcn_mfma_f32_16x16x32_bf16(kf[nj][1], aq[mf][1], z, 0, 0, 0); \
                    st[nj] = z;                                                         \
                }                                                                       \
                const bool diag = (tk0 + 64 > f0);                                      \
                float pv[4][4];                                                         \
                _Pragma("unroll")                                                       \
                for (int nj = 0; nj < 4; nj++)                                          \
                    _Pragma("unroll")                                                   \
                    for (int r = 0; r < 4; r++)                                         \
                        pv[nj][r] = exp2f(st[nj][r]);                                   \
                if (diag) {                                                             \
                    _Pragma("unroll")                                                   \
                    for (int nj = 0; nj < 4; nj++) {                                    \
                        const int keyb = tk0 + nj * 16 + quad * 4;                      \
                        _Pragma("unroll")                                               \
                        for (int r = 0; r < 4; r++)                                     \
                            if (keyb + r > qg) pv[nj][r] = 0.f;                         \
                    }                                                                   \
                }                                                                       \
                _Pragma("unroll")                                                       \
                for (int nj = 0; nj < 4; nj++) {                                        \
                    const unsigned int pk0 = __builtin_amdgcn_perm(                     \
                        __float_as_uint(pv[nj][1]), __float_as_uint(pv[nj][0]), 0x07060302u); \
                    const unsigned int pk1 = __builtin_amdgcn_perm(                     \
                        __float_as_uint(pv[nj][3]), __float_as_uint(pv[nj][2]), 0x07060302u); \
                    *(uint2*)&pm[l16 * PST + nj * 16 + quad * 4] = make_uint2(pk0, pk1);\
                }                                                                       \
                __asm volatile("s_waitcnt lgkmcnt(0)" ::: "memory");                    \
                __builtin_amdgcn_s_setprio(1);                                          \
                const s16x8 ap0 = *(const s16x8*)&pm[l16 * PST + quad * 8];             \
                const s16x8 ap1 = *(const s16x8*)&pm[l16 * PST + 32 + quad * 8];        \
                lacc[mf] = __builtin_amdgcn_mfma_f32_16x16x32_bf16(ap0, onesf, lacc[mf], 0, 0, 0); \
                lacc[mf] = __builtin_amdgcn_mfma_f32_16x16x32_bf16(ap1, onesf, lacc[mf], 0, 0, 0); \
                _Pragma("unroll")                                                       \
                for (int ni = 0; ni < 4; ni++) {                                        \
                    yacc[mf][ni] = __builtin_amdgcn_mfma_f32_16x16x32_bf16(ap0, vf[ni][0], yacc[mf][ni], 0, 0, 0); \
                    yacc[mf][ni] = __builtin_amdgcn_mfma_f32_16x16x32_bf16(ap1, vf[ni][1], yacc[mf][ni], 0, 0, 0); \
                }                                                                       \
                __builtin_amdgcn_s_setprio(0);                                          \
            }                                                                           \
        }                                                                               \
    }

    for (int t = 0; t < ntiles; t += 2) {
        ATT_STEP(0, t);
        ATT_STEP(1, t + 1);
    }
#undef ATT_STEP

    // epilogue: lacc[mf][r] is the denominator for q = f0 + quad*4 + r
    const int bbi = bh >> 4, hh = bh & 15;
    #pragma unroll
    for (int mf = 0; mf < 2; mf++) {
        float linv[4];
        #pragma unroll
        for (int r = 0; r < 4; r++)
            linv[r] = 1.0f / lacc[mf][r];
        #pragma unroll
        for (int ni = 0; ni < 4; ni++)
            #pragma unroll
            for (int r = 0; r < 4; r++) {
                const int trow = q0w + mf * 16 + quad * 4 + r;
                yb[((size_t)bbi * TT + trow) * NE + hh * HD + ni * 16 + l16] =
                    f2bf(yacc[mf][ni][r] * linv[r]);
            }
    }
}

extern "C" void kernel_launch(void* const* d_in, const int* in_sizes, int n_in,
                              void* d_out, int out_size, void* d_ws, size_t ws_size,
                              hipStream_t stream) {
    const float* x      = (const float*)d_in[0];
    const float* ln_w   = (const float*)d_in[1];
    const float* ln_b   = (const float*)d_in[2];
    const float* W_attn = (const float*)d_in[3];
    const float* b_attn = (const float*)d_in[4];
    const float* W_proj = (const float*)d_in[5];
    const float* b_proj = (const float*)d_in[6];
    float* out = (float*)d_out;

    char* ws = (char*)d_ws;
    unsigned short* h    = (unsigned short*)ws;  ws += (size_t)MM * C_IN * 2;
    unsigned short* Wat  = (unsigned short*)ws;  ws += (size_t)N_QKV * C_IN * 2;
    unsigned short* Wpt  = (unsigned short*)ws;  ws += (size_t)NE * NE * 2;
    unsigned short* qbuf = (unsigned short*)ws;  ws += (size_t)MM * NE * 2;
    unsigned short* kbuf = (unsigned short*)ws;  ws += (size_t)MM * NE * 2;
    unsigned short* vtbf = (unsigned short*)ws;  ws += (size_t)MM * NE * 2;
    unsigned short* ybuf = (unsigned short*)ws;  ws += (size_t)MM * NE * 2;

    prep_kernel<<<MM + TCA_BLOCKS + TCP_BLOCKS, 256, 0, stream>>>(x, ln_w, ln_b, h,
                                                                  W_attn, Wat, W_proj, Wpt);
    gemm_bt<0><<<dim3(N_QKV / 128, MM / 128), 256, 0, stream>>>(h, Wat, b_attn, qbuf, kbuf, vtbf,
                                                                MM, N_QKV, C_IN);
    attn_kernel<<<64 * 8, 512, 0, stream>>>(qbuf, kbuf, vtbf, ybuf);
    gemm_bt<1><<<dim3(NE / 128, MM / 128), 256, 0, stream>>>(ybuf, Wpt, b_proj, out, nullptr, nullptr,
                                                             MM, NE, NE);
}